// Round 1
// baseline (386.114 us; speedup 1.0000x reference)
//
#include <hip/hip_runtime.h>

#define BB 8192
#define TT 2048

// z pre-scaled by -log2(e): sigmoid(z_orig) = 1/(1+exp(-z_orig)) = rcp(1 + exp2(z))
__device__ __forceinline__ float sig2(float z) {
    return __builtin_amdgcn_rcpf(1.f + __builtin_amdgcn_exp2f(z));
}

__global__ __launch_bounds__(64) void bkt_main(
    const float* __restrict__ x, const float* __restrict__ y,
    const float* __restrict__ Wxh, const float* __restrict__ Whh,
    const float* __restrict__ bh, const float* __restrict__ Wy,
    const float* __restrict__ by, const float* __restrict__ prior,
    float* __restrict__ corrects, float* __restrict__ latents,
    float* __restrict__ partials)
{
    const int b = blockIdx.x * 64 + threadIdx.x;
    const float NL2E = -1.44269504088896340736f; // -log2(e)

    // uniform weights, pre-scaled so sigmoid is rcp(1+exp2(.))
    float wxh[4], bhv[4], byv[4], whh[4][4], wy[4][4];
#pragma unroll
    for (int j = 0; j < 4; ++j) {
        wxh[j] = Wxh[j] * NL2E;
        bhv[j] = bh[j] * NL2E;
        byv[j] = by[j] * NL2E;
#pragma unroll
        for (int k = 0; k < 4; ++k) {
            whh[k][j] = Whh[k * 4 + j] * NL2E;
            wy[k][j]  = Wy[k * 4 + j] * NL2E;
        }
    }

    const float* xr = x + (size_t)b * TT;
    const float* yr = y + (size_t)b * TT;
    float* cr = corrects + (size_t)b * TT;
    float* lr = latents  + (size_t)b * TT;

    float h0 = 0.f, h1 = 0.f, h2 = 0.f, h3 = 0.f;
    float lat = prior[0];
    float lacc = 0.f; // sum of log2(arg); convert to ln at the end

    float4 xv = *(const float4*)xr;
    float4 yv = *(const float4*)yr;

    for (int t0 = 0; t0 < TT; t0 += 4) {
        const int tn = (t0 + 4 < TT) ? (t0 + 4) : (TT - 4); // safe redundant last read
        float4 xn = *(const float4*)(xr + tn);
        float4 yn = *(const float4*)(yr + tn);
        float xa[4], ya[4], ca[4], la[4];
        *(float4*)xa = xv; *(float4*)ya = yv;
#pragma unroll
        for (int k = 0; k < 4; ++k) {
            // p = sigmoid(h @ Wy + by) ; l,f,g,s = p0..p3
            float zl = fmaf(h3, wy[3][0], fmaf(h2, wy[2][0], fmaf(h1, wy[1][0], fmaf(h0, wy[0][0], byv[0]))));
            float zf = fmaf(h3, wy[3][1], fmaf(h2, wy[2][1], fmaf(h1, wy[1][1], fmaf(h0, wy[0][1], byv[1]))));
            float zg = fmaf(h3, wy[3][2], fmaf(h2, wy[2][2], fmaf(h1, wy[1][2], fmaf(h0, wy[0][2], byv[2]))));
            float zs = fmaf(h3, wy[3][3], fmaf(h2, wy[2][3], fmaf(h1, wy[1][3], fmaf(h0, wy[0][3], byv[3]))));
            float pl = sig2(zl), pf = sig2(zf), pg = sig2(zg), ps = sig2(zs);

            // m_t == latent (exact algebraic identity), so:
            float correct = fmaf(lat, (1.f - ps) - pg, pg); // lat*(1-s) + (1-lat)*g
            float nlat    = fmaf(lat, (1.f - pf) - pl, pl); // lat*(1-f) + (1-lat)*l

            // h_new = sigmoid(x*Wxh + h@Whh + bh)
            float zb0 = fmaf(xa[k], wxh[0], bhv[0]);
            float zb1 = fmaf(xa[k], wxh[1], bhv[1]);
            float zb2 = fmaf(xa[k], wxh[2], bhv[2]);
            float zb3 = fmaf(xa[k], wxh[3], bhv[3]);
            float z0 = fmaf(h3, whh[3][0], fmaf(h2, whh[2][0], fmaf(h1, whh[1][0], fmaf(h0, whh[0][0], zb0))));
            float z1 = fmaf(h3, whh[3][1], fmaf(h2, whh[2][1], fmaf(h1, whh[1][1], fmaf(h0, whh[0][1], zb1))));
            float z2 = fmaf(h3, whh[3][2], fmaf(h2, whh[2][2], fmaf(h1, whh[1][2], fmaf(h0, whh[0][2], zb2))));
            float z3 = fmaf(h3, whh[3][3], fmaf(h2, whh[2][3], fmaf(h1, whh[1][3], fmaf(h0, whh[0][3], zb3))));

            // loss term: y ? log(c) : log(1-c), c clipped to [eps, 1-eps]
            float c = fminf(fmaxf(correct, 1e-7f), 1.f - 1e-7f);
            float arg = fmaf(ya[k], fmaf(2.f, c, -1.f), 1.f - c); // y*c + (1-y)*(1-c)
            lacc += __builtin_amdgcn_logf(arg); // log2

            ca[k] = correct;
            la[k] = nlat;
            lat = nlat;
            h0 = sig2(z0); h1 = sig2(z1); h2 = sig2(z2); h3 = sig2(z3);
        }
        *(float4*)(cr + t0) = *(float4*)ca;
        *(float4*)(lr + t0) = *(float4*)la;
        xv = xn; yv = yn;
    }

    // single-wave block reduction of loss partial
#pragma unroll
    for (int off = 32; off; off >>= 1) lacc += __shfl_down(lacc, off);
    if (threadIdx.x == 0) partials[blockIdx.x] = lacc;
}

__global__ __launch_bounds__(64) void bkt_loss(const float* __restrict__ partials, int n,
                                               float* __restrict__ out_loss)
{
    double s = 0.0;
    for (int i = threadIdx.x; i < n; i += 64) s += (double)partials[i];
#pragma unroll
    for (int off = 32; off; off >>= 1) s += __shfl_down(s, off);
    if (threadIdx.x == 0)
        *out_loss = (float)(-s * 0.69314718055994530942 / ((double)BB * (double)TT));
}

extern "C" void kernel_launch(void* const* d_in, const int* in_sizes, int n_in,
                              void* d_out, int out_size, void* d_ws, size_t ws_size,
                              hipStream_t stream)
{
    const float* x     = (const float*)d_in[0];
    const float* y     = (const float*)d_in[1];
    const float* Wxh   = (const float*)d_in[2];
    const float* Whh   = (const float*)d_in[3];
    const float* bh    = (const float*)d_in[4];
    const float* Wy    = (const float*)d_in[5];
    const float* by    = (const float*)d_in[6];
    const float* prior = (const float*)d_in[7];

    float* out      = (float*)d_out;
    float* corrects = out;                          // (B,T)
    float* latents  = out + (size_t)BB * TT;        // (B,T)
    float* lossp    = out + (size_t)2 * BB * TT;    // scalar
    float* partials = (float*)d_ws;

    bkt_main<<<BB / 64, 64, 0, stream>>>(x, y, Wxh, Whh, bh, Wy, by, prior,
                                         corrects, latents, partials);
    bkt_loss<<<1, 64, 0, stream>>>(partials, BB / 64, lossp);
}

// Round 2
// 183.695 us; speedup vs baseline: 2.1019x; 2.1019x over previous
//
#include <hip/hip_runtime.h>

#define BB 8192
#define TT 2048

// z pre-scaled by -log2(e): sigmoid(z_orig) = rcp(1 + exp2(z))
__device__ __forceinline__ float sig2(float z) {
    return __builtin_amdgcn_rcpf(1.f + __builtin_amdgcn_exp2f(z));
}

// broadcast lane L (0..3) of each 4-lane quad via DPP quad_perm (full-rate VALU)
template<int L>
__device__ __forceinline__ float qb(float v) {
    return __builtin_bit_cast(float,
        __builtin_amdgcn_mov_dpp(__builtin_bit_cast(int, v), L * 0x55, 0xF, 0xF, true));
}

__global__ __launch_bounds__(256) void bkt_main(
    const float* __restrict__ x, const float* __restrict__ y,
    const float* __restrict__ Wxh, const float* __restrict__ Whh,
    const float* __restrict__ bh, const float* __restrict__ Wy,
    const float* __restrict__ by, const float* __restrict__ prior,
    float* __restrict__ corrects, float* __restrict__ latents,
    float* __restrict__ partials)
{
    const int tid = blockIdx.x * 256 + threadIdx.x;
    const int q   = tid & 3;   // which h-dim this lane owns
    const int b   = tid >> 2;  // row
    const float NL2E = -1.44269504088896340736f; // -log2(e)

    // per-lane column-q weights, pre-scaled for exp2-based sigmoid
    float wyc[4], whc[4];
#pragma unroll
    for (int k = 0; k < 4; ++k) {
        wyc[k] = Wy[k * 4 + q]  * NL2E;
        whc[k] = Whh[k * 4 + q] * NL2E;
    }
    const float wxq = Wxh[q] * NL2E;
    const float bhq = bh[q]  * NL2E;
    const float byq = by[q]  * NL2E;

    const float* xr = x + (size_t)b * TT;
    const float* yr = y + (size_t)b * TT;
    float* cr = corrects + (size_t)b * TT;
    float* lr = latents  + (size_t)b * TT;

    float h = 0.f;             // this lane's h-dim
    float lat = prior[0];      // replicated across the quad
    float lacc = 0.f;          // log2 accum (each quad counts 4x; scaled later)

    // chunk of 16 timesteps: lane q owns steps 4q..4q+3 of the chunk
    float xq[4], yq[4], myc[4], myl[4];
    *(float4*)xq = *(const float4*)(xr + 4 * q);
    *(float4*)yq = *(const float4*)(yr + 4 * q);

    for (int t0 = 0; t0 < TT; t0 += 16) {
        const int tn = (t0 + 16 < TT) ? (t0 + 16) : t0; // last iter: harmless reload
        float xn[4], yn[4];
        *(float4*)xn = *(const float4*)(xr + tn + 4 * q);
        *(float4*)yn = *(const float4*)(yr + tn + 4 * q);

#define STEP(s)                                                                        \
        {                                                                              \
            float hb0 = qb<0>(h), hb1 = qb<1>(h), hb2 = qb<2>(h), hb3 = qb<3>(h);      \
            float zy = fmaf(hb3, wyc[3], fmaf(hb2, wyc[2],                             \
                        fmaf(hb1, wyc[1], fmaf(hb0, wyc[0], byq))));                   \
            float p  = sig2(zy);                                                       \
            float pl = qb<0>(p), pf = qb<1>(p), pg = qb<2>(p), ps = qb<3>(p);          \
            float correct = fmaf(lat, (1.f - ps) - pg, pg);                            \
            float nlat    = fmaf(lat, (1.f - pf) - pl, pl);                            \
            float xs = qb<(s) / 4>(xq[(s) & 3]);                                       \
            float ys = qb<(s) / 4>(yq[(s) & 3]);                                       \
            float zh = fmaf(hb3, whc[3], fmaf(hb2, whc[2],                             \
                        fmaf(hb1, whc[1], fmaf(hb0, whc[0], fmaf(xs, wxq, bhq)))));    \
            float c   = fminf(fmaxf(correct, 1e-7f), 1.f - 1e-7f);                     \
            float arg = fmaf(ys, fmaf(2.f, c, -1.f), 1.f - c);                         \
            lacc += __builtin_amdgcn_logf(arg);                                        \
            if (q == (s) / 4) { myc[(s) & 3] = correct; myl[(s) & 3] = nlat; }         \
            lat = nlat;                                                                \
            h = sig2(zh);                                                              \
        }

        STEP(0)  STEP(1)  STEP(2)  STEP(3)
        STEP(4)  STEP(5)  STEP(6)  STEP(7)
        STEP(8)  STEP(9)  STEP(10) STEP(11)
        STEP(12) STEP(13) STEP(14) STEP(15)
#undef STEP

        // quad writes a full contiguous 64B span per row (full-line stores)
        *(float4*)(cr + t0 + 4 * q) = *(float4*)myc;
        *(float4*)(lr + t0 + 4 * q) = *(float4*)myl;

        *(float4*)xq = *(float4*)xn;
        *(float4*)yq = *(float4*)yn;
    }

    // wave reduction (each row counted 4x -> scaled in bkt_loss)
#pragma unroll
    for (int off = 32; off; off >>= 1) lacc += __shfl_down(lacc, off);
    if ((threadIdx.x & 63) == 0) partials[tid >> 6] = lacc;
}

__global__ __launch_bounds__(64) void bkt_loss(const float* __restrict__ partials, int n,
                                               float* __restrict__ out_loss)
{
    double s = 0.0;
    for (int i = threadIdx.x; i < n; i += 64) s += (double)partials[i];
#pragma unroll
    for (int off = 32; off; off >>= 1) s += __shfl_down(s, off);
    if (threadIdx.x == 0)
        *out_loss = (float)(-s * 0.69314718055994530942 / (4.0 * (double)BB * (double)TT));
}

extern "C" void kernel_launch(void* const* d_in, const int* in_sizes, int n_in,
                              void* d_out, int out_size, void* d_ws, size_t ws_size,
                              hipStream_t stream)
{
    const float* x     = (const float*)d_in[0];
    const float* y     = (const float*)d_in[1];
    const float* Wxh   = (const float*)d_in[2];
    const float* Whh   = (const float*)d_in[3];
    const float* bh    = (const float*)d_in[4];
    const float* Wy    = (const float*)d_in[5];
    const float* by    = (const float*)d_in[6];
    const float* prior = (const float*)d_in[7];

    float* out      = (float*)d_out;
    float* corrects = out;                          // (B,T)
    float* latents  = out + (size_t)BB * TT;        // (B,T)
    float* lossp    = out + (size_t)2 * BB * TT;    // scalar
    float* partials = (float*)d_ws;                 // 512 floats

    const int threads = BB * 4;                     // 4 lanes per row
    bkt_main<<<threads / 256, 256, 0, stream>>>(x, y, Wxh, Whh, bh, Wy, by, prior,
                                                corrects, latents, partials);
    bkt_loss<<<1, 64, 0, stream>>>(partials, threads / 64, lossp);
}